// Round 1
// baseline (65.780 us; speedup 1.0000x reference)
//
#include <hip/hip_runtime.h>
#include <math.h>

// Problem constants (from setup_inputs: N=128, P=16, S=128)
#define NB    128                 // batches
#define PP    16                  // points per polyline
#define SS    128                 // image size
#define NSEG  (PP - 1)            // 15 segments
#define KPTS  (NSEG * SS)         // 1920 interpolated points per batch
#define RAD   4                   // Gaussian truncation radius: exp(-25)=1.4e-11 negligible
#define TAPS  (2 * RAD + 1)       // 9
#define TCOLS 32                  // output columns (t) handled per block
#define HY    (TCOLS + 2 * RAD)   // 40  histogram y-window width
#define HX    (SS + 1 + 2 * RAD)  // 137 histogram x rows (x in [0,128] + pad 4 each side)
#define TMPX  (SS + TAPS - 1)     // 136 tmp rows (logical x in [-4,131])

__global__ __launch_bounds__(256) void plotline_kernel(
    const float* __restrict__ points, float* __restrict__ out)
{
    const int n   = blockIdx.x >> 2;      // batch
    const int q   = blockIdx.x & 3;       // column quarter
    const int y0  = q * TCOLS;            // first output column of this block
    const int tid = threadIdx.x;

    __shared__ float Hl[HX][HY];          // histogram, x-padded by RAD rows each side
    __shared__ float Tl[TMPX][TCOLS];     // after y-convolution
    __shared__ float pts[PP * 2];

    // W[j] = exp(-(j-RAD)^2), f32-correctly-rounded constants
    const float W[TAPS] = {
        1.1253517471925912e-07f,  // exp(-16)
        1.2340980408667956e-04f,  // exp(-9)
        1.8315638888734179e-02f,  // exp(-4)
        3.6787944117144233e-01f,  // exp(-1)
        1.0f,
        3.6787944117144233e-01f,
        1.8315638888734179e-02f,
        1.2340980408667956e-04f,
        1.1253517471925912e-07f
    };

    // ---- zero LDS ----
    for (int i = tid; i < HX * HY;      i += 256) ((float*)Hl)[i] = 0.0f;
    for (int i = tid; i < TMPX * TCOLS; i += 256) ((float*)Tl)[i] = 0.0f;
    if (tid < PP * 2) pts[tid] = points[n * PP * 2 + tid];
    __syncthreads();

    // ---- histogram of rounded interpolated points ----
    // Must match numpy elementwise semantics exactly: separate RN mul/mul/add
    // (no fma contraction), then round-half-to-even. t = i/128 and 1-t are
    // exact in f32 (power-of-two denominators).
    for (int idx = tid; idx < KPTS; idx += 256) {
        const int j = idx >> 7;       // segment index 0..14
        const int i = idx & 127;      // step 0..127 (last step of each segment dropped)
        const float t   = (float)i * (1.0f / 128.0f);
        const float omt = 1.0f - t;
        const float x0 = pts[j * 2 + 0], y0p = pts[j * 2 + 1];
        const float x1 = pts[j * 2 + 2], y1p = pts[j * 2 + 3];
        const float vx = __fadd_rn(__fmul_rn(omt, x0), __fmul_rn(t, x1));
        const float vy = __fadd_rn(__fmul_rn(omt, y0p), __fmul_rn(t, y1p));
        const int ix = (int)rintf(vx);            // round half-to-even
        const int iy = (int)rintf(vy);
        const int yy = iy - y0 + RAD;             // window-local y
        if ((unsigned)ix <= 128u && (unsigned)yy < (unsigned)HY) {
            atomicAdd(&Hl[ix + RAD][yy], 1.0f);   // ds_add_f32
        }
    }
    __syncthreads();

    // ---- pass 1: y-direction 9-tap conv: Tl[xi][tl] = sum_dy Hl[xi][tl+dy]*W[dy]
    // Tl row xi corresponds to logical x = xi - RAD; Hl row xi is already that x.
    for (int idx = tid; idx < TMPX * TCOLS; idx += 256) {
        const int xi = idx >> 5;
        const int tl = idx & 31;
        float acc = 0.0f;
        #pragma unroll
        for (int d = 0; d < TAPS; ++d)
            acc += Hl[xi][tl + d] * W[d];
        Tl[xi][tl] = acc;
    }
    __syncthreads();

    // ---- pass 2: x-direction 9-tap conv + tanh + store ----
    for (int idx = tid; idx < SS * TCOLS; idx += 256) {
        const int s  = idx >> 5;
        const int tl = idx & 31;
        float acc = 0.0f;
        #pragma unroll
        for (int d = 0; d < TAPS; ++d)
            acc += Tl[s + d][tl] * W[d];
        // tanh(acc), acc >= 0: (1 - e^{-2x}) / (1 + e^{-2x})
        const float e = __expf(-2.0f * acc);
        const float r = (1.0f - e) / (1.0f + e);
        out[(n * SS + s) * SS + (y0 + tl)] = r;
    }
}

extern "C" void kernel_launch(void* const* d_in, const int* in_sizes, int n_in,
                              void* d_out, int out_size, void* d_ws, size_t ws_size,
                              hipStream_t stream) {
    const float* points = (const float*)d_in[0];
    float* out = (float*)d_out;
    // 128 batches x 4 column-quarters
    plotline_kernel<<<dim3(NB * 4), dim3(256), 0, stream>>>(points, out);
}

// Round 2
// 63.968 us; speedup vs baseline: 1.0283x; 1.0283x over previous
//
#include <hip/hip_runtime.h>
#include <math.h>

// Problem constants (from setup_inputs: N=128, P=16, S=128)
#define NB    128                 // batches
#define PP    16                  // points per polyline
#define SS    128                 // image size
#define NSEG  (PP - 1)            // 15 segments
#define KPTS  (NSEG * SS)         // 1920 interpolated points per batch
#define RAD   4                   // Gaussian truncation radius: exp(-25)=1.4e-11 negligible
#define TAPS  (2 * RAD + 1)       // 9
#define TCOLS 32                  // output columns (t) handled per block
#define HY    (TCOLS + 2 * RAD)   // 40  histogram y-window width (mult of 4)
#define HX    (SS + 1 + 2 * RAD)  // 137 histogram x rows (x in [0,128] + pad 4 each side)
#define TMPX  (SS + TAPS - 1)     // 136 tmp rows (logical x in [-4,131])

__device__ __forceinline__ float conv9(const float* w, const float* W) {
    float acc = 0.0f;
    #pragma unroll
    for (int d = 0; d < TAPS; ++d) acc += w[d] * W[d];
    return acc;
}

__device__ __forceinline__ float fast_tanh_pos(float x) {
    // x >= 0: tanh(x) = (1 - e^{-2x}) / (1 + e^{-2x})
    const float e = __expf(-2.0f * x);
    return (1.0f - e) / (1.0f + e);
}

__global__ __launch_bounds__(256) void plotline_kernel(
    const float* __restrict__ points, float* __restrict__ out)
{
    const int n   = blockIdx.x >> 2;      // batch
    const int q   = blockIdx.x & 3;       // column quarter
    const int y0  = q * TCOLS;            // first output column of this block
    const int tid = threadIdx.x;

    __shared__ float Hl[HX][HY];          // histogram, x-padded by RAD rows each side
    __shared__ float Tl[TMPX][TCOLS];     // after y-convolution (fully overwritten, no zero needed)
    __shared__ float pts[PP * 2];

    // W[j] = exp(-(j-RAD)^2), f32-correctly-rounded constants
    const float W[TAPS] = {
        1.1253517471925912e-07f,  // exp(-16)
        1.2340980408667956e-04f,  // exp(-9)
        1.8315638888734179e-02f,  // exp(-4)
        3.6787944117144233e-01f,  // exp(-1)
        1.0f,
        3.6787944117144233e-01f,
        1.8315638888734179e-02f,
        1.2340980408667956e-04f,
        1.1253517471925912e-07f
    };

    // ---- zero histogram (float4: 5480/4 = 1370 vec stores) ----
    {
        float4* h4 = (float4*)&Hl[0][0];
        const float4 z = make_float4(0.f, 0.f, 0.f, 0.f);
        for (int i = tid; i < (HX * HY) / 4; i += 256) h4[i] = z;
    }
    if (tid < PP * 2) pts[tid] = points[n * PP * 2 + tid];
    __syncthreads();

    // ---- histogram of rounded interpolated points ----
    // Must match numpy elementwise semantics exactly: separate RN mul/mul/add
    // (no fma contraction), then round-half-to-even. t = i/128 and 1-t are
    // exact in f32 (power-of-two denominators).
    for (int idx = tid; idx < KPTS; idx += 256) {
        const int j = idx >> 7;       // segment index 0..14
        const int i = idx & 127;      // step 0..127 (last step of each segment dropped)
        const float t   = (float)i * (1.0f / 128.0f);
        const float omt = 1.0f - t;
        const float x0 = pts[j * 2 + 0], y0p = pts[j * 2 + 1];
        const float x1 = pts[j * 2 + 2], y1p = pts[j * 2 + 3];
        const float vx = __fadd_rn(__fmul_rn(omt, x0), __fmul_rn(t, x1));
        const float vy = __fadd_rn(__fmul_rn(omt, y0p), __fmul_rn(t, y1p));
        const int ix = (int)rintf(vx);            // round half-to-even
        const int iy = (int)rintf(vy);
        const int yy = iy - y0 + RAD;             // window-local y
        if ((unsigned)ix <= 128u && (unsigned)yy < (unsigned)HY) {
            atomicAdd(&Hl[ix + RAD][yy], 1.0f);   // ds_add_f32
        }
    }
    __syncthreads();

    // ---- pass 1: y-direction 9-tap conv, register sliding window ----
    // Each task: 4 outputs Tl[xi][tl0..tl0+3] from 12-float window (3x b128).
    // Alignment: Hl row stride 40 floats, tl0%4==0 -> 16B aligned. Max col
    // index tl0+11 = 39 < HY=40.
    for (int idx = tid; idx < TMPX * (TCOLS / 4); idx += 256) {
        const int xi  = idx >> 3;
        const int tl0 = (idx & 7) * 4;
        const float4* rp = (const float4*)&Hl[xi][tl0];
        const float4 a = rp[0], b = rp[1], c = rp[2];
        const float w[12] = {a.x, a.y, a.z, a.w, b.x, b.y, b.z, b.w, c.x, c.y, c.z, c.w};
        float4 o;
        o.x = conv9(w + 0, W);
        o.y = conv9(w + 1, W);
        o.z = conv9(w + 2, W);
        o.w = conv9(w + 3, W);
        *(float4*)&Tl[xi][tl0] = o;
    }
    __syncthreads();

    // ---- pass 2: x-direction 9-tap conv on a 4x4 register tile + tanh ----
    // 256 threads = 32 (s-tiles) x 8 (tl-tiles), exactly one tile each.
    {
        const int s0  = (tid >> 3) * 4;       // 0..124
        const int tl0 = (tid & 7) * 4;        // 0..28
        float4 r[12];
        #pragma unroll
        for (int i = 0; i < 12; ++i)
            r[i] = *(const float4*)&Tl[s0 + i][tl0];   // rows s0..s0+11 <= 135 = TMPX-1
        #pragma unroll
        for (int i = 0; i < 4; ++i) {
            float4 acc = make_float4(0.f, 0.f, 0.f, 0.f);
            #pragma unroll
            for (int d = 0; d < TAPS; ++d) {
                acc.x += r[i + d].x * W[d];
                acc.y += r[i + d].y * W[d];
                acc.z += r[i + d].z * W[d];
                acc.w += r[i + d].w * W[d];
            }
            float4 res;
            res.x = fast_tanh_pos(acc.x);
            res.y = fast_tanh_pos(acc.y);
            res.z = fast_tanh_pos(acc.z);
            res.w = fast_tanh_pos(acc.w);
            *(float4*)&out[(n * SS + s0 + i) * SS + (y0 + tl0)] = res;
        }
    }
}

extern "C" void kernel_launch(void* const* d_in, const int* in_sizes, int n_in,
                              void* d_out, int out_size, void* d_ws, size_t ws_size,
                              hipStream_t stream) {
    const float* points = (const float*)d_in[0];
    float* out = (float*)d_out;
    // 128 batches x 4 column-quarters
    plotline_kernel<<<dim3(NB * 4), dim3(256), 0, stream>>>(points, out);
}